// Round 2
// baseline (9889.721 us; speedup 1.0000x reference)
//
#include <hip/hip_runtime.h>
#include <stdint.h>

#define N_NODES 100000
#define N_EDGES 1000000
#define D_IN 128
#define D_OUT 64
#define N_REL 4
#define OUT_STRIDE (N_REL * D_OUT)   // 256

__device__ inline float b2f(unsigned short u) {
    union { unsigned int i; float f; } v;
    v.i = ((unsigned int)u) << 16;
    return v.f;
}
__device__ inline unsigned short f2b(float f) {
    union { float f; unsigned int i; } v;
    v.f = f;
    unsigned int r = v.i + 0x7FFF + ((v.i >> 16) & 1);   // round-nearest-even
    return (unsigned short)(r >> 16);
}

// flag=1 if mask is 1-byte bools, 0 if int32 (bytes at i%4!=0 all zero).
__global__ __launch_bounds__(256) void detect_mask_kernel(const uint8_t* __restrict__ mask,
                                                          int* __restrict__ flag) {
    int any = 0;
    for (int i = threadIdx.x; i < 65536; i += 256)
        if ((i & 3) && mask[i]) any = 1;
    if (any) atomicOr(flag, 1);
}

__device__ inline bool read_mask(const uint8_t* mask8, int bytemode, size_t idx) {
    return bytemode ? (mask8[idx] != 0) : (((const int*)mask8)[idx] != 0);
}

// masked in-degree, all relations
__global__ __launch_bounds__(256) void deg_kernel(const int* __restrict__ dst,
                                                  const uint8_t* __restrict__ mask,
                                                  const int* __restrict__ flag,
                                                  float* __restrict__ deg) {
    int e = blockIdx.x * blockDim.x + threadIdx.x;
    if (e >= N_EDGES) return;
    int bytemode = *flag;
    int d = dst[e];
#pragma unroll
    for (int r = 0; r < N_REL; ++r) {
        if (read_mask(mask, bytemode, (size_t)r * N_EDGES + e))
            atomicAdd(&deg[(size_t)r * N_NODES + d], 1.0f);
    }
}

__global__ __launch_bounds__(256) void norm_kernel(float* __restrict__ deg) {
    int i = blockIdx.x * blockDim.x + threadIdx.x;
    if (i >= N_REL * N_NODES) return;
    deg[i] = 1.0f / sqrtf(fmaxf(deg[i], 1.0f));
}

// one hop: agg[dst] += norm[src] * hin[src], masked; 32 lanes/edge
template <int BF16IN>
__global__ __launch_bounds__(256) void scatter_kernel(const void* __restrict__ hin_,
                                                      const int* __restrict__ src,
                                                      const int* __restrict__ dst,
                                                      const uint8_t* __restrict__ mask,
                                                      int rel,
                                                      const int* __restrict__ flag,
                                                      const float* __restrict__ normr,
                                                      float* __restrict__ agg) {
    int tid  = blockIdx.x * blockDim.x + threadIdx.x;
    int e    = tid >> 5;
    int lane = tid & 31;
    if (e >= N_EDGES) return;
    if (!read_mask(mask, *flag, (size_t)rel * N_EDGES + e)) return;
    int s = src[e];
    int d = dst[e];
    float c = normr[s];
    float4 v;
    if (BF16IN) {
        ushort4 u = ((const ushort4*)((const unsigned short*)hin_ + (size_t)s * D_IN))[lane];
        v = make_float4(b2f(u.x), b2f(u.y), b2f(u.z), b2f(u.w));
    } else {
        v = ((const float4*)((const float*)hin_ + (size_t)s * D_IN))[lane];
    }
    float* o = agg + (size_t)d * D_IN + lane * 4;
    atomicAdd(o + 0, v.x * c);
    atomicAdd(o + 1, v.y * c);
    atomicAdd(o + 2, v.z * c);
    atomicAdd(o + 3, v.w * c);
}

__global__ __launch_bounds__(256) void scale_kernel(float* __restrict__ h,
                                                    const float* __restrict__ normr) {
    int i = blockIdx.x * blockDim.x + threadIdx.x;
    if (i >= N_NODES * (D_IN / 4)) return;
    int n = i >> 5;
    float c = normr[n];
    float4 v = ((float4*)h)[i];
    v.x *= c; v.y *= c; v.z *= c; v.w *= c;
    ((float4*)h)[i] = v;
}

__global__ __launch_bounds__(256) void scale_convert_kernel(const float* __restrict__ agg,
                                                            const float* __restrict__ normr,
                                                            unsigned short* __restrict__ h1b) {
    int i = blockIdx.x * blockDim.x + threadIdx.x;
    if (i >= N_NODES * (D_IN / 4)) return;
    int n = i >> 5;
    float c = normr[n];
    float4 v = ((const float4*)agg)[i];
    ushort4 u;
    u.x = f2b(v.x * c); u.y = f2b(v.y * c); u.z = f2b(v.z * c); u.w = f2b(v.w * c);
    ((ushort4*)h1b)[i] = u;
}

// out[n][j] = relu(b[j] + sum_k [x|h1|h2][n][k] * W[k][j]); h1 is bf16
__global__ __launch_bounds__(256) void gemm_kernel(const float* __restrict__ x,
                                                   const unsigned short* __restrict__ h1b,
                                                   const float* __restrict__ h2,
                                                   const float* __restrict__ W,
                                                   const float* __restrict__ b,
                                                   float* __restrict__ out) {
    __shared__ float Wl[64 * 64];
    const int j    = threadIdx.x & 63;
    const int ni   = threadIdx.x >> 6;
    const int base = blockIdx.x * 64;

    float acc[16];
#pragma unroll
    for (int t = 0; t < 16; ++t) acc[t] = 0.0f;

    for (int c = 0; c < 6; ++c) {
        const float* Wc = W + (size_t)c * 64 * 64;
#pragma unroll
        for (int i = 0; i < 16; ++i)
            Wl[threadIdx.x + i * 256] = Wc[threadIdx.x + i * 256];
        __syncthreads();

        const int seg  = c >> 1;
        const int koff = (c & 1) * 64;
        const bool isb = (seg == 1);
        const float* pf = (seg == 0) ? x : h2;

#pragma unroll 4
        for (int k4 = 0; k4 < 16; ++k4) {
            float w0 = Wl[(k4 * 4 + 0) * 64 + j];
            float w1 = Wl[(k4 * 4 + 1) * 64 + j];
            float w2 = Wl[(k4 * 4 + 2) * 64 + j];
            float w3 = Wl[(k4 * 4 + 3) * 64 + j];
#pragma unroll
            for (int t = 0; t < 16; ++t) {
                int n = base + ni + 4 * t;
                if (n < N_NODES) {
                    float4 fv;
                    if (isb) {
                        ushort4 u = *(const ushort4*)(h1b + (size_t)n * D_IN + koff + k4 * 4);
                        fv = make_float4(b2f(u.x), b2f(u.y), b2f(u.z), b2f(u.w));
                    } else {
                        fv = *(const float4*)(pf + (size_t)n * D_IN + koff + k4 * 4);
                    }
                    acc[t] += fv.x * w0 + fv.y * w1 + fv.z * w2 + fv.w * w3;
                }
            }
        }
        __syncthreads();
    }

    float bias = b[j];
#pragma unroll
    for (int t = 0; t < 16; ++t) {
        int n = base + ni + 4 * t;
        if (n < N_NODES) {
            float v = acc[t] + bias;
            out[(size_t)n * OUT_STRIDE + j] = fmaxf(v, 0.0f);
        }
    }
}

extern "C" void kernel_launch(void* const* d_in, const int* in_sizes, int n_in,
                              void* d_out, int out_size, void* d_ws, size_t ws_size,
                              hipStream_t stream) {
    const float*   x    = (const float*)d_in[0];
    const int*     src  = (const int*)d_in[1];
    const int*     dst  = (const int*)d_in[2];
    const uint8_t* mask = (const uint8_t*)d_in[3];
    const float*   W    = (const float*)d_in[4];     // [4][384][64]
    const float*   b    = (const float*)d_in[5];     // [4][64]
    float*         out  = (float*)d_out;             // [N][256]

    // ws: flag(pad 64 f) | norm[4N] f32 | h1b[N*128] bf16 | agg[N*128] f32 = 78.4MB
    int*            flag = (int*)d_ws;
    float*          norm = (float*)d_ws + 64;
    unsigned short* h1b  = (unsigned short*)(norm + (size_t)N_REL * N_NODES);
    float*          agg  = (float*)(h1b + (size_t)N_NODES * D_IN);

    hipMemsetAsync(d_ws, 0, (64 + (size_t)N_REL * N_NODES) * sizeof(float), stream);
    detect_mask_kernel<<<1, 256, 0, stream>>>(mask, flag);
    deg_kernel<<<(N_EDGES + 255) / 256, 256, 0, stream>>>(dst, mask, flag, norm);
    norm_kernel<<<(N_REL * N_NODES + 255) / 256, 256, 0, stream>>>(norm);

    const int scatter_grid = (N_EDGES * 32) / 256;
    const int scale_grid   = (N_NODES * (D_IN / 4) + 255) / 256;
    const int gemm_grid    = (N_NODES + 63) / 64;
    const size_t agg_bytes = (size_t)N_NODES * D_IN * sizeof(float);

    for (int r = 0; r < N_REL; ++r) {
        const float* nr = norm + (size_t)r * N_NODES;

        // hop 1: agg = A(norm*x); h1b = bf16(norm*agg)
        hipMemsetAsync(agg, 0, agg_bytes, stream);
        scatter_kernel<0><<<scatter_grid, 256, 0, stream>>>(x, src, dst, mask, r, flag, nr, agg);
        scale_convert_kernel<<<scale_grid, 256, 0, stream>>>(agg, nr, h1b);

        // hop 2: agg = A(h1b); h2 = norm*agg in place
        hipMemsetAsync(agg, 0, agg_bytes, stream);
        scatter_kernel<1><<<scatter_grid, 256, 0, stream>>>(h1b, src, dst, mask, r, flag, nr, agg);
        scale_kernel<<<scale_grid, 256, 0, stream>>>(agg, nr);

        gemm_kernel<<<gemm_grid, 256, 0, stream>>>(
            x, h1b, agg,
            W + (size_t)r * (3 * D_IN) * D_OUT,
            b + (size_t)r * D_OUT,
            out + (size_t)r * D_OUT);
    }
}

// Round 3
// 3786.925 us; speedup vs baseline: 2.6115x; 2.6115x over previous
//
#include <hip/hip_runtime.h>
#include <stdint.h>

#define N_NODES 100000
#define N_EDGES 1000000
#define D_IN 128
#define D_OUT 64
#define N_REL 4
#define OUT_STRIDE (N_REL * D_OUT)   // 256

__device__ inline float b2f(unsigned short u) {
    union { unsigned int i; float f; } v;
    v.i = ((unsigned int)u) << 16;
    return v.f;
}
__device__ inline unsigned short f2b(float f) {
    union { float f; unsigned int i; } v;
    v.f = f;
    unsigned int r = v.i + 0x7FFF + ((v.i >> 16) & 1);   // rne
    return (unsigned short)(r >> 16);
}

// flag=1 if mask is 1-byte bools, 0 if int32
__global__ __launch_bounds__(256) void detect_mask_kernel(const uint8_t* __restrict__ mask,
                                                          int* __restrict__ flag) {
    int any = 0;
    for (int i = threadIdx.x; i < 65536; i += 256)
        if ((i & 3) && mask[i]) any = 1;
    if (any) atomicOr(flag, 1);
}

__device__ inline bool read_mask(const uint8_t* mask8, int bytemode, size_t idx) {
    return bytemode ? (mask8[idx] != 0) : (((const int*)mask8)[idx] != 0);
}

// masked in-degree (float) for norms, all relations
__global__ __launch_bounds__(256) void deg_kernel(const int* __restrict__ dst,
                                                  const uint8_t* __restrict__ mask,
                                                  const int* __restrict__ flag,
                                                  float* __restrict__ deg) {
    int e = blockIdx.x * blockDim.x + threadIdx.x;
    if (e >= N_EDGES) return;
    int bytemode = *flag;
    int d = dst[e];
#pragma unroll
    for (int r = 0; r < N_REL; ++r) {
        if (read_mask(mask, bytemode, (size_t)r * N_EDGES + e))
            atomicAdd(&deg[(size_t)r * N_NODES + d], 1.0f);
    }
}

__global__ __launch_bounds__(256) void norm_kernel(float* __restrict__ deg) {
    int i = blockIdx.x * blockDim.x + threadIdx.x;
    if (i >= N_REL * N_NODES) return;
    deg[i] = 1.0f / sqrtf(fmaxf(deg[i], 1.0f));
}

// unmasked in-degree histogram (int) for CSR
__global__ __launch_bounds__(256) void count_kernel(const int* __restrict__ dst,
                                                    int* __restrict__ degi) {
    int e = blockIdx.x * blockDim.x + threadIdx.x;
    if (e >= N_EDGES) return;
    atomicAdd(&degi[dst[e]], 1);
}

// single-workgroup exclusive scan: degi[N] -> row_ptr[N+1], cursor[N]
__global__ __launch_bounds__(256) void scan_kernel(const int* __restrict__ degi,
                                                   int* __restrict__ row_ptr,
                                                   int* __restrict__ cursor) {
    __shared__ int part[256];
    const int T = 256;
    int t = threadIdx.x;
    int chunk = (N_NODES + T - 1) / T;
    int lo = t * chunk, hi = min(lo + chunk, N_NODES);
    int s = 0;
    for (int i = lo; i < hi; ++i) s += degi[i];
    part[t] = s;
    __syncthreads();
    if (t == 0) {
        int run = 0;
        for (int i = 0; i < T; ++i) { int v = part[i]; part[i] = run; run += v; }
    }
    __syncthreads();
    int run = part[t];
    for (int i = lo; i < hi; ++i) {
        row_ptr[i] = run; cursor[i] = run; run += degi[i];
    }
    if (t == T - 1) row_ptr[N_NODES] = run;
}

// fill CSR: csr_src[pos]=src, csr_w[pos][r]=mask_r ? norm_r[src] : 0
__global__ __launch_bounds__(256) void fill_kernel(const int* __restrict__ src,
                                                   const int* __restrict__ dst,
                                                   const uint8_t* __restrict__ mask,
                                                   const int* __restrict__ flag,
                                                   const float* __restrict__ norm,
                                                   int* __restrict__ cursor,
                                                   int* __restrict__ csr_src,
                                                   float4* __restrict__ csr_w) {
    int e = blockIdx.x * blockDim.x + threadIdx.x;
    if (e >= N_EDGES) return;
    int bm = *flag;
    int d = dst[e], s = src[e];
    int pos = atomicAdd(&cursor[d], 1);
    csr_src[pos] = s;
    float4 w;
    w.x = read_mask(mask, bm, (size_t)0 * N_EDGES + e) ? norm[0 * N_NODES + s] : 0.0f;
    w.y = read_mask(mask, bm, (size_t)1 * N_EDGES + e) ? norm[1 * N_NODES + s] : 0.0f;
    w.z = read_mask(mask, bm, (size_t)2 * N_EDGES + e) ? norm[2 * N_NODES + s] : 0.0f;
    w.w = read_mask(mask, bm, (size_t)3 * N_EDGES + e) ? norm[3 * N_NODES + s] : 0.0f;
    csr_w[pos] = w;
}

// one hop, gather form: hout[d] = bf16( norm[d] * sum_e w[e] * hin[src[e]] )
// one wave (64 lanes) per node; lane covers 2 of 128 features.
template <int BF16IN>
__global__ __launch_bounds__(256) void gather_kernel(const void* __restrict__ hin_,
                                                     const int* __restrict__ row_ptr,
                                                     const int* __restrict__ csr_src,
                                                     const float* __restrict__ csr_w,
                                                     int rel,
                                                     const float* __restrict__ normr,
                                                     unsigned short* __restrict__ hout) {
    int wid  = (blockIdx.x * blockDim.x + threadIdx.x) >> 6;   // node
    int lane = threadIdx.x & 63;
    if (wid >= N_NODES) return;
    int e0 = row_ptr[wid], e1 = row_ptr[wid + 1];
    float a0 = 0.0f, a1 = 0.0f;
    for (int base = e0; base < e1; base += 64) {
        int m = min(64, e1 - base);
        int   s_l = 0;
        float w_l = 0.0f;
        if (lane < m) {
            s_l = csr_src[base + lane];
            w_l = csr_w[(size_t)(base + lane) * 4 + rel];
        }
        for (int k = 0; k < m; ++k) {
            float w = __shfl(w_l, k);
            if (w != 0.0f) {               // wave-uniform branch
                int s = __shfl(s_l, k);
                if (BF16IN) {
                    unsigned int u = *(const unsigned int*)
                        ((const unsigned short*)hin_ + (size_t)s * D_IN + lane * 2);
                    a0 += w * b2f((unsigned short)(u & 0xFFFF));
                    a1 += w * b2f((unsigned short)(u >> 16));
                } else {
                    float2 v = *(const float2*)
                        ((const float*)hin_ + (size_t)s * D_IN + lane * 2);
                    a0 += w * v.x;
                    a1 += w * v.y;
                }
            }
        }
    }
    float c = normr[wid];
    unsigned int o = ((unsigned int)f2b(a1 * c) << 16) | f2b(a0 * c);
    *(unsigned int*)(hout + (size_t)wid * D_IN + lane * 2) = o;
}

// out[n][j] = relu(b[j] + sum_k [x|h1|h2][n][k] W[k][j]); x fp32, h1/h2 bf16
__global__ __launch_bounds__(256) void gemm_kernel(const float* __restrict__ x,
                                                   const unsigned short* __restrict__ h1b,
                                                   const unsigned short* __restrict__ h2b,
                                                   const float* __restrict__ W,
                                                   const float* __restrict__ b,
                                                   float* __restrict__ out) {
    __shared__ float Wl[64 * 64];
    const int j    = threadIdx.x & 63;
    const int ni   = threadIdx.x >> 6;
    const int base = blockIdx.x * 64;

    float acc[16];
#pragma unroll
    for (int t = 0; t < 16; ++t) acc[t] = 0.0f;

    for (int c = 0; c < 6; ++c) {
        const float* Wc = W + (size_t)c * 64 * 64;
#pragma unroll
        for (int i = 0; i < 16; ++i)
            Wl[threadIdx.x + i * 256] = Wc[threadIdx.x + i * 256];
        __syncthreads();

        const int seg  = c >> 1;
        const int koff = (c & 1) * 64;
        const unsigned short* pb = (seg == 1) ? h1b : h2b;

#pragma unroll 4
        for (int k4 = 0; k4 < 16; ++k4) {
            float w0 = Wl[(k4 * 4 + 0) * 64 + j];
            float w1 = Wl[(k4 * 4 + 1) * 64 + j];
            float w2 = Wl[(k4 * 4 + 2) * 64 + j];
            float w3 = Wl[(k4 * 4 + 3) * 64 + j];
#pragma unroll
            for (int t = 0; t < 16; ++t) {
                int n = base + ni + 4 * t;
                if (n < N_NODES) {
                    float4 fv;
                    if (seg == 0) {
                        fv = *(const float4*)(x + (size_t)n * D_IN + koff + k4 * 4);
                    } else {
                        ushort4 u = *(const ushort4*)(pb + (size_t)n * D_IN + koff + k4 * 4);
                        fv = make_float4(b2f(u.x), b2f(u.y), b2f(u.z), b2f(u.w));
                    }
                    acc[t] += fv.x * w0 + fv.y * w1 + fv.z * w2 + fv.w * w3;
                }
            }
        }
        __syncthreads();
    }

    float bias = b[j];
#pragma unroll
    for (int t = 0; t < 16; ++t) {
        int n = base + ni + 4 * t;
        if (n < N_NODES) {
            float v = acc[t] + bias;
            out[(size_t)n * OUT_STRIDE + j] = fmaxf(v, 0.0f);
        }
    }
}

extern "C" void kernel_launch(void* const* d_in, const int* in_sizes, int n_in,
                              void* d_out, int out_size, void* d_ws, size_t ws_size,
                              hipStream_t stream) {
    const float*   x    = (const float*)d_in[0];
    const int*     src  = (const int*)d_in[1];
    const int*     dst  = (const int*)d_in[2];
    const uint8_t* mask = (const uint8_t*)d_in[3];
    const float*   W    = (const float*)d_in[4];     // [4][384][64]
    const float*   b    = (const float*)d_in[5];     // [4][64]
    float*         out  = (float*)d_out;             // [N][256]

    // ws layout (ints/floats, 16B-aligned where needed), total ~74 MB:
    // flag[64] | norm[4N]f | degi[N] | row_ptr[N+16] | cursor[N] | csr_src[E]
    // | csr_w[E]float4 | h1b[N*128]bf16 | h2b[N*128]bf16
    int*            flag    = (int*)d_ws;
    float*          norm    = (float*)d_ws + 64;
    int*            degi    = (int*)(norm + (size_t)N_REL * N_NODES);
    int*            row_ptr = degi + N_NODES;
    int*            cursor  = row_ptr + N_NODES + 16;
    int*            csr_src = cursor + N_NODES;
    float4*         csr_w   = (float4*)(csr_src + N_EDGES);
    unsigned short* h1b     = (unsigned short*)(csr_w + N_EDGES);
    unsigned short* h2b     = h1b + (size_t)N_NODES * D_IN;

    // zero: flag + norm + degi (contiguous region)
    hipMemsetAsync(d_ws, 0, (64 + (size_t)N_REL * N_NODES + N_NODES) * sizeof(int), stream);

    detect_mask_kernel<<<1, 256, 0, stream>>>(mask, flag);
    deg_kernel<<<(N_EDGES + 255) / 256, 256, 0, stream>>>(dst, mask, flag, norm);
    norm_kernel<<<(N_REL * N_NODES + 255) / 256, 256, 0, stream>>>(norm);

    count_kernel<<<(N_EDGES + 255) / 256, 256, 0, stream>>>(dst, degi);
    scan_kernel<<<1, 256, 0, stream>>>(degi, row_ptr, cursor);
    fill_kernel<<<(N_EDGES + 255) / 256, 256, 0, stream>>>(src, dst, mask, flag, norm,
                                                           cursor, csr_src, csr_w);

    const int gather_grid = (N_NODES * 64 + 255) / 256;   // 1 wave per node
    const int gemm_grid   = (N_NODES + 63) / 64;

    for (int r = 0; r < N_REL; ++r) {
        const float* nr = norm + (size_t)r * N_NODES;

        gather_kernel<0><<<gather_grid, 256, 0, stream>>>(
            x, row_ptr, csr_src, (const float*)csr_w, r, nr, h1b);
        gather_kernel<1><<<gather_grid, 256, 0, stream>>>(
            h1b, row_ptr, csr_src, (const float*)csr_w, r, nr, h2b);

        gemm_kernel<<<gemm_grid, 256, 0, stream>>>(
            x, h1b, h2b,
            W + (size_t)r * (3 * D_IN) * D_OUT,
            b + (size_t)r * D_OUT,
            out + (size_t)r * D_OUT);
    }
}

// Round 4
// 1109.007 us; speedup vs baseline: 8.9176x; 3.4147x over previous
//
#include <hip/hip_runtime.h>
#include <stdint.h>

#define N_NODES 100000
#define N_EDGES 1000000
#define D_IN 128
#define D_OUT 64
#define N_REL 4
#define OUT_STRIDE (N_REL * D_OUT)   // 256

typedef short s16x8 __attribute__((ext_vector_type(8)));
typedef float f32x4 __attribute__((ext_vector_type(4)));

__device__ inline float b2f(unsigned short u) {
    union { unsigned int i; float f; } v;
    v.i = ((unsigned int)u) << 16;
    return v.f;
}
__device__ inline unsigned short f2b(float f) {
    union { float f; unsigned int i; } v;
    v.f = f;
    unsigned int r = v.i + 0x7FFF + ((v.i >> 16) & 1);   // rne
    return (unsigned short)(r >> 16);
}

// flag=1 if mask is 1-byte bools, 0 if int32
__global__ __launch_bounds__(256) void detect_mask_kernel(const uint8_t* __restrict__ mask,
                                                          int* __restrict__ flag) {
    int any = 0;
    for (int i = threadIdx.x; i < 65536; i += 256)
        if ((i & 3) && mask[i]) any = 1;
    if (any) atomicOr(flag, 1);
}

__device__ inline bool read_mask(const uint8_t* mask8, int bytemode, size_t idx) {
    return bytemode ? (mask8[idx] != 0) : (((const int*)mask8)[idx] != 0);
}

// masked in-degree (float) for norms, all relations
__global__ __launch_bounds__(256) void deg_kernel(const int* __restrict__ dst,
                                                  const uint8_t* __restrict__ mask,
                                                  const int* __restrict__ flag,
                                                  float* __restrict__ deg) {
    int e = blockIdx.x * blockDim.x + threadIdx.x;
    if (e >= N_EDGES) return;
    int bytemode = *flag;
    int d = dst[e];
#pragma unroll
    for (int r = 0; r < N_REL; ++r) {
        if (read_mask(mask, bytemode, (size_t)r * N_EDGES + e))
            atomicAdd(&deg[(size_t)r * N_NODES + d], 1.0f);
    }
}

__global__ __launch_bounds__(256) void norm_kernel(float* __restrict__ deg) {
    int i = blockIdx.x * blockDim.x + threadIdx.x;
    if (i >= N_REL * N_NODES) return;
    deg[i] = 1.0f / sqrtf(fmaxf(deg[i], 1.0f));
}

// unmasked in-degree histogram (int) for CSR
__global__ __launch_bounds__(256) void count_kernel(const int* __restrict__ dst,
                                                    int* __restrict__ degi) {
    int e = blockIdx.x * blockDim.x + threadIdx.x;
    if (e >= N_EDGES) return;
    atomicAdd(&degi[dst[e]], 1);
}

// single-workgroup exclusive scan: degi[N] -> row_ptr[N+1], cursor[N]
__global__ __launch_bounds__(256) void scan_kernel(const int* __restrict__ degi,
                                                   int* __restrict__ row_ptr,
                                                   int* __restrict__ cursor) {
    __shared__ int part[256];
    const int T = 256;
    int t = threadIdx.x;
    int chunk = (N_NODES + T - 1) / T;
    int lo = t * chunk, hi = min(lo + chunk, N_NODES);
    int s = 0;
    for (int i = lo; i < hi; ++i) s += degi[i];
    part[t] = s;
    __syncthreads();
    if (t == 0) {
        int run = 0;
        for (int i = 0; i < T; ++i) { int v = part[i]; part[i] = run; run += v; }
    }
    __syncthreads();
    int run = part[t];
    for (int i = lo; i < hi; ++i) {
        row_ptr[i] = run; cursor[i] = run; run += degi[i];
    }
    if (t == T - 1) row_ptr[N_NODES] = run;
}

// fill CSR: csr_src[pos]=src, csr_w[pos][r]=mask_r ? norm_r[src] : 0
__global__ __launch_bounds__(256) void fill_kernel(const int* __restrict__ src,
                                                   const int* __restrict__ dst,
                                                   const uint8_t* __restrict__ mask,
                                                   const int* __restrict__ flag,
                                                   const float* __restrict__ norm,
                                                   int* __restrict__ cursor,
                                                   int* __restrict__ csr_src,
                                                   float4* __restrict__ csr_w) {
    int e = blockIdx.x * blockDim.x + threadIdx.x;
    if (e >= N_EDGES) return;
    int bm = *flag;
    int d = dst[e], s = src[e];
    int pos = atomicAdd(&cursor[d], 1);
    csr_src[pos] = s;
    float4 w;
    w.x = read_mask(mask, bm, (size_t)0 * N_EDGES + e) ? norm[0 * N_NODES + s] : 0.0f;
    w.y = read_mask(mask, bm, (size_t)1 * N_EDGES + e) ? norm[1 * N_NODES + s] : 0.0f;
    w.z = read_mask(mask, bm, (size_t)2 * N_EDGES + e) ? norm[2 * N_NODES + s] : 0.0f;
    w.w = read_mask(mask, bm, (size_t)3 * N_EDGES + e) ? norm[3 * N_NODES + s] : 0.0f;
    csr_w[pos] = w;
}

// pack W[r][384][64] fp32 -> Wpk frags [r][ks][nb][lane][8] bf16
__global__ __launch_bounds__(256) void pack_w_kernel(const float* __restrict__ W,
                                                     unsigned short* __restrict__ Wpk) {
    int t = blockIdx.x * blockDim.x + threadIdx.x;   // 4*12*4*64 = 12288
    if (t >= N_REL * 12 * 4 * 64) return;
    int lane = t & 63;
    int nb   = (t >> 6) & 3;
    int ks   = (t >> 8) % 12;
    int r    = t / 3072;
    const float* Wr = W + (size_t)r * 384 * 64;
    int k0 = ks * 32 + (lane >> 4) * 8;
    int n  = nb * 16 + (lane & 15);
    unsigned short* o = Wpk + (size_t)t * 8;
#pragma unroll
    for (int i = 0; i < 8; ++i)
        o[i] = f2b(Wr[(size_t)(k0 + i) * 64 + n]);
}

// one hop, gather form: hout[d] = bf16( norm[d] * sum_e w[e] * hin[src[e]] )
template <int BF16IN>
__global__ __launch_bounds__(256) void gather_kernel(const void* __restrict__ hin_,
                                                     const int* __restrict__ row_ptr,
                                                     const int* __restrict__ csr_src,
                                                     const float* __restrict__ csr_w,
                                                     int rel,
                                                     const float* __restrict__ normr,
                                                     unsigned short* __restrict__ hout) {
    int wid  = (blockIdx.x * blockDim.x + threadIdx.x) >> 6;   // node
    int lane = threadIdx.x & 63;
    if (wid >= N_NODES) return;
    int e0 = row_ptr[wid], e1 = row_ptr[wid + 1];
    float a0 = 0.0f, a1 = 0.0f;
    for (int base = e0; base < e1; base += 64) {
        int m = min(64, e1 - base);
        int   s_l = 0;
        float w_l = 0.0f;
        if (lane < m) {
            s_l = csr_src[base + lane];
            w_l = csr_w[(size_t)(base + lane) * 4 + rel];
        }
        for (int k = 0; k < m; ++k) {
            float w = __shfl(w_l, k);
            if (w != 0.0f) {               // wave-uniform branch
                int s = __shfl(s_l, k);
                if (BF16IN) {
                    unsigned int u = *(const unsigned int*)
                        ((const unsigned short*)hin_ + (size_t)s * D_IN + lane * 2);
                    a0 += w * b2f((unsigned short)(u & 0xFFFF));
                    a1 += w * b2f((unsigned short)(u >> 16));
                } else {
                    float2 v = *(const float2*)
                        ((const float*)hin_ + (size_t)s * D_IN + lane * 2);
                    a0 += w * v.x;
                    a1 += w * v.y;
                }
            }
        }
    }
    float c = normr[wid];
    unsigned int o = ((unsigned int)f2b(a1 * c) << 16) | f2b(a0 * c);
    *(unsigned int*)(hout + (size_t)wid * D_IN + lane * 2) = o;
}

// MFMA GEMM: out[n][j] = relu(bias[j] + sum_k [x|h1|h2][n][k] W[k][j])
// per relation; Wpk/bias/out pre-offset. 4 waves/block; wave = 16 rows x 64 cols.
__global__ __launch_bounds__(256) void gemm_mfma_kernel(const float* __restrict__ x,
                                                        const unsigned short* __restrict__ h1b,
                                                        const unsigned short* __restrict__ h2b,
                                                        const unsigned short* __restrict__ Wpk,
                                                        const float* __restrict__ bias,
                                                        float* __restrict__ out) {
    const int wave = threadIdx.x >> 6;
    const int lane = threadIdx.x & 63;
    const int rb   = blockIdx.x * 64 + wave * 16;
    const int row  = min(rb + (lane & 15), N_NODES - 1);
    const int kq   = (lane >> 4) * 8;          // k sub-offset within 32-step

    f32x4 acc0 = {0.f, 0.f, 0.f, 0.f};
    f32x4 acc1 = {0.f, 0.f, 0.f, 0.f};
    f32x4 acc2 = {0.f, 0.f, 0.f, 0.f};
    f32x4 acc3 = {0.f, 0.f, 0.f, 0.f};

    const s16x8* Wf = (const s16x8*)Wpk;

#pragma unroll
    for (int ks = 0; ks < 12; ++ks) {
        s16x8 a;
        const int koff = (ks & 3) * 32 + kq;
        if (ks < 4) {
            const float* p = x + (size_t)row * D_IN + koff;
            float4 f0 = *(const float4*)p;
            float4 f1 = *(const float4*)(p + 4);
            a[0] = (short)f2b(f0.x); a[1] = (short)f2b(f0.y);
            a[2] = (short)f2b(f0.z); a[3] = (short)f2b(f0.w);
            a[4] = (short)f2b(f1.x); a[5] = (short)f2b(f1.y);
            a[6] = (short)f2b(f1.z); a[7] = (short)f2b(f1.w);
        } else {
            const unsigned short* hp = (ks < 8) ? h1b : h2b;
            a = *(const s16x8*)(hp + (size_t)row * D_IN + koff);
        }
        const s16x8* bks = Wf + ks * 256 + lane;
        acc0 = __builtin_amdgcn_mfma_f32_16x16x32_bf16(a, bks[0],   acc0, 0, 0, 0);
        acc1 = __builtin_amdgcn_mfma_f32_16x16x32_bf16(a, bks[64],  acc1, 0, 0, 0);
        acc2 = __builtin_amdgcn_mfma_f32_16x16x32_bf16(a, bks[128], acc2, 0, 0, 0);
        acc3 = __builtin_amdgcn_mfma_f32_16x16x32_bf16(a, bks[192], acc3, 0, 0, 0);
    }

    // D layout: col = lane&15, row = (lane>>4)*4 + i
    const int orow0 = rb + (lane >> 4) * 4;
    const int jc    = lane & 15;
    f32x4 accs[4] = {acc0, acc1, acc2, acc3};
#pragma unroll
    for (int nb = 0; nb < 4; ++nb) {
        float bz = bias[nb * 16 + jc];
#pragma unroll
        for (int i = 0; i < 4; ++i) {
            int n = orow0 + i;
            if (n < N_NODES)
                out[(size_t)n * OUT_STRIDE + nb * 16 + jc] = fmaxf(accs[nb][i] + bz, 0.0f);
        }
    }
}

extern "C" void kernel_launch(void* const* d_in, const int* in_sizes, int n_in,
                              void* d_out, int out_size, void* d_ws, size_t ws_size,
                              hipStream_t stream) {
    const float*   x    = (const float*)d_in[0];
    const int*     src  = (const int*)d_in[1];
    const int*     dst  = (const int*)d_in[2];
    const uint8_t* mask = (const uint8_t*)d_in[3];
    const float*   W    = (const float*)d_in[4];     // [4][384][64]
    const float*   b    = (const float*)d_in[5];     // [4][64]
    float*         out  = (float*)d_out;             // [N][256]

    // ws: flag[64]i | norm[4N]f | degi[N] | row_ptr[N+16] | cursor[N] | csr_src[E]
    //   | csr_w[E]f4 | h1b[N*128]bf16 | h2b[N*128]bf16 | Wpk[12288*8]bf16  ~74.5MB
    int*            flag    = (int*)d_ws;
    float*          norm    = (float*)d_ws + 64;
    int*            degi    = (int*)(norm + (size_t)N_REL * N_NODES);
    int*            row_ptr = degi + N_NODES;
    int*            cursor  = row_ptr + N_NODES + 16;
    int*            csr_src = cursor + N_NODES;
    float4*         csr_w   = (float4*)(csr_src + N_EDGES);
    unsigned short* h1b     = (unsigned short*)(csr_w + N_EDGES);
    unsigned short* h2b     = h1b + (size_t)N_NODES * D_IN;
    unsigned short* Wpk     = h2b + (size_t)N_NODES * D_IN;

    // zero: flag + norm + degi (contiguous)
    hipMemsetAsync(d_ws, 0, (64 + (size_t)N_REL * N_NODES + N_NODES) * sizeof(int), stream);

    detect_mask_kernel<<<1, 256, 0, stream>>>(mask, flag);
    deg_kernel<<<(N_EDGES + 255) / 256, 256, 0, stream>>>(dst, mask, flag, norm);
    norm_kernel<<<(N_REL * N_NODES + 255) / 256, 256, 0, stream>>>(norm);

    count_kernel<<<(N_EDGES + 255) / 256, 256, 0, stream>>>(dst, degi);
    scan_kernel<<<1, 256, 0, stream>>>(degi, row_ptr, cursor);
    fill_kernel<<<(N_EDGES + 255) / 256, 256, 0, stream>>>(src, dst, mask, flag, norm,
                                                           cursor, csr_src, csr_w);
    pack_w_kernel<<<48, 256, 0, stream>>>(W, Wpk);

    const int gather_grid = (N_NODES * 64 + 255) / 256;   // 1 wave per node
    const int gemm_grid   = (N_NODES + 63) / 64;

    for (int r = 0; r < N_REL; ++r) {
        const float* nr = norm + (size_t)r * N_NODES;

        gather_kernel<0><<<gather_grid, 256, 0, stream>>>(
            x, row_ptr, csr_src, (const float*)csr_w, r, nr, h1b);
        gather_kernel<1><<<gather_grid, 256, 0, stream>>>(
            h1b, row_ptr, csr_src, (const float*)csr_w, r, nr, h2b);

        gemm_mfma_kernel<<<gemm_grid, 256, 0, stream>>>(
            x, h1b, h2b,
            Wpk + (size_t)r * 3072 * 8,
            b + (size_t)r * D_OUT,
            out + (size_t)r * D_OUT);
    }
}

// Round 5
// 911.038 us; speedup vs baseline: 10.8554x; 1.2173x over previous
//
#include <hip/hip_runtime.h>
#include <hip/hip_fp16.h>
#include <stdint.h>

#define N_NODES 100000
#define N_EDGES 1000000
#define D_IN 128
#define D_OUT 64
#define N_REL 4
#define OUT_STRIDE (N_REL * D_OUT)   // 256

#define SCAN_CHUNK 512
#define N_SBLK ((N_NODES + SCAN_CHUNK - 1) / SCAN_CHUNK)   // 196 (<=256)

typedef short s16x8 __attribute__((ext_vector_type(8)));
typedef float f32x4 __attribute__((ext_vector_type(4)));

__device__ inline float b2f(unsigned short u) {
    union { unsigned int i; float f; } v;
    v.i = ((unsigned int)u) << 16;
    return v.f;
}
__device__ inline unsigned short f2b(float f) {
    union { float f; unsigned int i; } v;
    v.f = f;
    unsigned int r = v.i + 0x7FFF + ((v.i >> 16) & 1);   // rne
    return (unsigned short)(r >> 16);
}

// flag=1 if mask is 1-byte bools, 0 if int32
__global__ __launch_bounds__(256) void detect_mask_kernel(const uint8_t* __restrict__ mask,
                                                          int* __restrict__ flag) {
    int any = 0;
    for (int i = threadIdx.x; i < 65536; i += 256)
        if ((i & 3) && mask[i]) any = 1;
    if (any) atomicOr(flag, 1);
}

__device__ inline bool read_mask(const uint8_t* mask8, int bytemode, size_t idx) {
    return bytemode ? (mask8[idx] != 0) : (((const int*)mask8)[idx] != 0);
}

// masked in-degree (float, per relation) + unmasked histogram (int) in one pass
__global__ __launch_bounds__(256) void deg_kernel(const int* __restrict__ dst,
                                                  const uint8_t* __restrict__ mask,
                                                  const int* __restrict__ flag,
                                                  float* __restrict__ deg,
                                                  int* __restrict__ degi) {
    int e = blockIdx.x * blockDim.x + threadIdx.x;
    if (e >= N_EDGES) return;
    int bytemode = *flag;
    int d = dst[e];
    atomicAdd(&degi[d], 1);
#pragma unroll
    for (int r = 0; r < N_REL; ++r) {
        if (read_mask(mask, bytemode, (size_t)r * N_EDGES + e))
            atomicAdd(&deg[(size_t)r * N_NODES + d], 1.0f);
    }
}

__global__ __launch_bounds__(256) void norm_kernel(float* __restrict__ deg) {
    int i = blockIdx.x * blockDim.x + threadIdx.x;
    if (i >= N_REL * N_NODES) return;
    deg[i] = 1.0f / sqrtf(fmaxf(deg[i], 1.0f));
}

// ---- parallel exclusive scan of degi[N] -> row_ptr[N+1], cursor[N] ----
__global__ __launch_bounds__(256) void scan_reduce_kernel(const int* __restrict__ degi,
                                                          int* __restrict__ bsum) {
    __shared__ int sm[256];
    int b = blockIdx.x, t = threadIdx.x;
    int i0 = b * SCAN_CHUNK + t;
    int v = 0;
    if (i0 < N_NODES) v += degi[i0];
    if (i0 + 256 < N_NODES && (i0 + 256) < (b + 1) * SCAN_CHUNK) v += degi[i0 + 256];
    sm[t] = v;
    __syncthreads();
    for (int s = 128; s > 0; s >>= 1) {
        if (t < s) sm[t] += sm[t + s];
        __syncthreads();
    }
    if (t == 0) bsum[b] = sm[0];
}

__global__ __launch_bounds__(256) void scan_mid_kernel(const int* __restrict__ bsum,
                                                       int* __restrict__ boff,
                                                       int* __restrict__ row_ptr) {
    __shared__ int sm[256];
    int t = threadIdx.x;
    int v = (t < N_SBLK) ? bsum[t] : 0;
    sm[t] = v;
    __syncthreads();
    for (int s = 1; s < 256; s <<= 1) {
        int u = (t >= s) ? sm[t - s] : 0;
        __syncthreads();
        sm[t] += u;
        __syncthreads();
    }
    if (t < N_SBLK) boff[t] = sm[t] - v;       // exclusive
    if (t == N_SBLK - 1) row_ptr[N_NODES] = sm[t];   // total edges
}

__global__ __launch_bounds__(256) void scan_final_kernel(const int* __restrict__ degi,
                                                         const int* __restrict__ boff,
                                                         int* __restrict__ row_ptr,
                                                         int* __restrict__ cursor) {
    __shared__ int sm[256];
    int b = blockIdx.x, t = threadIdx.x;
    int i0 = b * SCAN_CHUNK + 2 * t;
    int v0 = (i0 < N_NODES) ? degi[i0] : 0;
    int v1 = (i0 + 1 < N_NODES) ? degi[i0 + 1] : 0;
    int inc = v0 + v1;
    sm[t] = inc;
    __syncthreads();
    for (int s = 1; s < 256; s <<= 1) {
        int u = (t >= s) ? sm[t - s] : 0;
        __syncthreads();
        sm[t] += u;
        __syncthreads();
    }
    int exc = sm[t] - inc + boff[b];
    if (i0 < N_NODES)     { row_ptr[i0]     = exc;      cursor[i0]     = exc; }
    if (i0 + 1 < N_NODES) { row_ptr[i0 + 1] = exc + v0; cursor[i0 + 1] = exc + v0; }
}

// fill CSR: csr_src[pos]=src, csr_wh[pos][r] = fp16( mask_r ? norm_r[src] : 0 )
__global__ __launch_bounds__(256) void fill_kernel(const int* __restrict__ src,
                                                   const int* __restrict__ dst,
                                                   const uint8_t* __restrict__ mask,
                                                   const int* __restrict__ flag,
                                                   const float* __restrict__ norm,
                                                   int* __restrict__ cursor,
                                                   int* __restrict__ csr_src,
                                                   unsigned short* __restrict__ csr_wh) {
    int e = blockIdx.x * blockDim.x + threadIdx.x;
    if (e >= N_EDGES) return;
    int bm = *flag;
    int d = dst[e], s = src[e];
    int pos = atomicAdd(&cursor[d], 1);
    csr_src[pos] = s;
    ushort4 uw;
    uw.x = __half_as_ushort(__float2half_rn(
        read_mask(mask, bm, (size_t)0 * N_EDGES + e) ? norm[0 * N_NODES + s] : 0.0f));
    uw.y = __half_as_ushort(__float2half_rn(
        read_mask(mask, bm, (size_t)1 * N_EDGES + e) ? norm[1 * N_NODES + s] : 0.0f));
    uw.z = __half_as_ushort(__float2half_rn(
        read_mask(mask, bm, (size_t)2 * N_EDGES + e) ? norm[2 * N_NODES + s] : 0.0f));
    uw.w = __half_as_ushort(__float2half_rn(
        read_mask(mask, bm, (size_t)3 * N_EDGES + e) ? norm[3 * N_NODES + s] : 0.0f));
    ((ushort4*)csr_wh)[pos] = uw;
}

// pack W[r][384][64] fp32 -> Wpk frags [r][ks][nb][lane][8] bf16
__global__ __launch_bounds__(256) void pack_w_kernel(const float* __restrict__ W,
                                                     unsigned short* __restrict__ Wpk) {
    int t = blockIdx.x * blockDim.x + threadIdx.x;   // 4*12*4*64 = 12288
    if (t >= N_REL * 12 * 4 * 64) return;
    int lane = t & 63;
    int nb   = (t >> 6) & 3;
    int ks   = (t >> 8) % 12;
    int r    = t / 3072;
    const float* Wr = W + (size_t)r * 384 * 64;
    int k0 = ks * 32 + (lane >> 4) * 8;
    int n  = nb * 16 + (lane & 15);
    unsigned short* o = Wpk + (size_t)t * 8;
#pragma unroll
    for (int i = 0; i < 8; ++i)
        o[i] = f2b(Wr[(size_t)(k0 + i) * 64 + n]);
}

// x fp32 -> bf16
__global__ __launch_bounds__(256) void xb_kernel(const float* __restrict__ x,
                                                 unsigned short* __restrict__ xb) {
    int i = blockIdx.x * blockDim.x + threadIdx.x;
    if (i >= N_NODES * (D_IN / 4)) return;
    float4 v = ((const float4*)x)[i];
    ushort4 u;
    u.x = f2b(v.x); u.y = f2b(v.y); u.z = f2b(v.z); u.w = f2b(v.w);
    ((ushort4*)xb)[i] = u;
}

// one hop, gather form: hout[d] = bf16( norm[d] * sum_e w[e] * hin[src[e]] )
template <int BF16IN>
__global__ __launch_bounds__(256) void gather_kernel(const void* __restrict__ hin_,
                                                     const int* __restrict__ row_ptr,
                                                     const int* __restrict__ csr_src,
                                                     const unsigned short* __restrict__ csr_wh,
                                                     int rel,
                                                     const float* __restrict__ normr,
                                                     unsigned short* __restrict__ hout) {
    int wid  = (blockIdx.x * blockDim.x + threadIdx.x) >> 6;   // node
    int lane = threadIdx.x & 63;
    if (wid >= N_NODES) return;
    int e0 = row_ptr[wid], e1 = row_ptr[wid + 1];
    float a0 = 0.0f, a1 = 0.0f;
    for (int base = e0; base < e1; base += 64) {
        int m = min(64, e1 - base);
        int   s_l = 0;
        float w_l = 0.0f;
        if (lane < m) {
            s_l = csr_src[base + lane];
            w_l = __half2float(((const __half*)csr_wh)[(size_t)(base + lane) * 4 + rel]);
        }
        for (int k = 0; k < m; ++k) {
            float w = __shfl(w_l, k);
            if (w != 0.0f) {               // wave-uniform branch
                int s = __shfl(s_l, k);
                if (BF16IN) {
                    unsigned int u = *(const unsigned int*)
                        ((const unsigned short*)hin_ + (size_t)s * D_IN + lane * 2);
                    a0 += w * b2f((unsigned short)(u & 0xFFFF));
                    a1 += w * b2f((unsigned short)(u >> 16));
                } else {
                    float2 v = *(const float2*)
                        ((const float*)hin_ + (size_t)s * D_IN + lane * 2);
                    a0 += w * v.x;
                    a1 += w * v.y;
                }
            }
        }
    }
    float c = normr[wid];
    unsigned int o = ((unsigned int)f2b(a1 * c) << 16) | f2b(a0 * c);
    *(unsigned int*)(hout + (size_t)wid * D_IN + lane * 2) = o;
}

// MFMA GEMM: out[n][j] = relu(bias[j] + sum_k [x|h1|h2][n][k] W[k][j])
__global__ __launch_bounds__(256) void gemm_mfma_kernel(const float* __restrict__ x,
                                                        const unsigned short* __restrict__ h1b,
                                                        const unsigned short* __restrict__ h2b,
                                                        const unsigned short* __restrict__ Wpk,
                                                        const float* __restrict__ bias,
                                                        float* __restrict__ out) {
    const int wave = threadIdx.x >> 6;
    const int lane = threadIdx.x & 63;
    const int rb   = blockIdx.x * 64 + wave * 16;
    const int row  = min(rb + (lane & 15), N_NODES - 1);
    const int kq   = (lane >> 4) * 8;

    f32x4 acc0 = {0.f, 0.f, 0.f, 0.f};
    f32x4 acc1 = {0.f, 0.f, 0.f, 0.f};
    f32x4 acc2 = {0.f, 0.f, 0.f, 0.f};
    f32x4 acc3 = {0.f, 0.f, 0.f, 0.f};

    const s16x8* Wf = (const s16x8*)Wpk;

#pragma unroll
    for (int ks = 0; ks < 12; ++ks) {
        s16x8 a;
        const int koff = (ks & 3) * 32 + kq;
        if (ks < 4) {
            const float* p = x + (size_t)row * D_IN + koff;
            float4 f0 = *(const float4*)p;
            float4 f1 = *(const float4*)(p + 4);
            a[0] = (short)f2b(f0.x); a[1] = (short)f2b(f0.y);
            a[2] = (short)f2b(f0.z); a[3] = (short)f2b(f0.w);
            a[4] = (short)f2b(f1.x); a[5] = (short)f2b(f1.y);
            a[6] = (short)f2b(f1.z); a[7] = (short)f2b(f1.w);
        } else {
            const unsigned short* hp = (ks < 8) ? h1b : h2b;
            a = *(const s16x8*)(hp + (size_t)row * D_IN + koff);
        }
        const s16x8* bks = Wf + ks * 256 + lane;
        acc0 = __builtin_amdgcn_mfma_f32_16x16x32_bf16(a, bks[0],   acc0, 0, 0, 0);
        acc1 = __builtin_amdgcn_mfma_f32_16x16x32_bf16(a, bks[64],  acc1, 0, 0, 0);
        acc2 = __builtin_amdgcn_mfma_f32_16x16x32_bf16(a, bks[128], acc2, 0, 0, 0);
        acc3 = __builtin_amdgcn_mfma_f32_16x16x32_bf16(a, bks[192], acc3, 0, 0, 0);
    }

    const int orow0 = rb + (lane >> 4) * 4;
    const int jc    = lane & 15;
    f32x4 accs[4] = {acc0, acc1, acc2, acc3};
#pragma unroll
    for (int nb = 0; nb < 4; ++nb) {
        float bz = bias[nb * 16 + jc];
#pragma unroll
        for (int i = 0; i < 4; ++i) {
            int n = orow0 + i;
            if (n < N_NODES)
                out[(size_t)n * OUT_STRIDE + nb * 16 + jc] = fmaxf(accs[nb][i] + bz, 0.0f);
        }
    }
}

extern "C" void kernel_launch(void* const* d_in, const int* in_sizes, int n_in,
                              void* d_out, int out_size, void* d_ws, size_t ws_size,
                              hipStream_t stream) {
    const float*   x    = (const float*)d_in[0];
    const int*     src  = (const int*)d_in[1];
    const int*     dst  = (const int*)d_in[2];
    const uint8_t* mask = (const uint8_t*)d_in[3];
    const float*   W    = (const float*)d_in[4];     // [4][384][64]
    const float*   b    = (const float*)d_in[5];     // [4][64]
    float*         out  = (float*)d_out;             // [N][256]

    // ws layout (bytes, in order):
    // flag[64]i | norm[4N]f | degi[N]i | row_ptr[N+16]i | cursor[N]i | bsum[256]i
    // | boff[256]i | csr_src[E]i | csr_wh[4E]h | Wpk bf16 | h1b bf16 | h2b bf16
    // | xb bf16 (optional) -> ~91.8MB with xb, ~66.2MB without
    int*            flag    = (int*)d_ws;
    float*          norm    = (float*)d_ws + 64;
    int*            degi    = (int*)(norm + (size_t)N_REL * N_NODES);
    int*            row_ptr = degi + N_NODES;
    int*            cursor  = row_ptr + N_NODES + 16;
    int*            bsum    = cursor + N_NODES;
    int*            boff    = bsum + 256;
    int*            csr_src = boff + 256;
    unsigned short* csr_wh  = (unsigned short*)(csr_src + N_EDGES);
    unsigned short* Wpk     = csr_wh + (size_t)4 * N_EDGES;
    unsigned short* h1b     = Wpk + 12288 * 8;
    unsigned short* h2b     = h1b + (size_t)N_NODES * D_IN;
    unsigned short* xb      = h2b + (size_t)N_NODES * D_IN;

    const size_t need_xb =
        (size_t)((char*)(xb + (size_t)N_NODES * D_IN) - (char*)d_ws);
    const int use_xb = (ws_size >= need_xb);

    // zero: flag + norm + degi (contiguous)
    hipMemsetAsync(d_ws, 0, (64 + (size_t)N_REL * N_NODES + N_NODES) * sizeof(int), stream);

    detect_mask_kernel<<<1, 256, 0, stream>>>(mask, flag);
    deg_kernel<<<(N_EDGES + 255) / 256, 256, 0, stream>>>(dst, mask, flag, norm, degi);
    norm_kernel<<<(N_REL * N_NODES + 255) / 256, 256, 0, stream>>>(norm);

    scan_reduce_kernel<<<N_SBLK, 256, 0, stream>>>(degi, bsum);
    scan_mid_kernel<<<1, 256, 0, stream>>>(bsum, boff, row_ptr);
    scan_final_kernel<<<N_SBLK, 256, 0, stream>>>(degi, boff, row_ptr, cursor);

    fill_kernel<<<(N_EDGES + 255) / 256, 256, 0, stream>>>(src, dst, mask, flag, norm,
                                                           cursor, csr_src, csr_wh);
    pack_w_kernel<<<48, 256, 0, stream>>>(W, Wpk);
    if (use_xb)
        xb_kernel<<<(N_NODES * (D_IN / 4) + 255) / 256, 256, 0, stream>>>(x, xb);

    const int gather_grid = (N_NODES * 64 + 255) / 256;   // 1 wave per node
    const int gemm_grid   = (N_NODES + 63) / 64;

    for (int r = 0; r < N_REL; ++r) {
        const float* nr = norm + (size_t)r * N_NODES;

        if (use_xb)
            gather_kernel<1><<<gather_grid, 256, 0, stream>>>(
                xb, row_ptr, csr_src, csr_wh, r, nr, h1b);
        else
            gather_kernel<0><<<gather_grid, 256, 0, stream>>>(
                x, row_ptr, csr_src, csr_wh, r, nr, h1b);

        gather_kernel<1><<<gather_grid, 256, 0, stream>>>(
            h1b, row_ptr, csr_src, csr_wh, r, nr, h2b);

        gemm_mfma_kernel<<<gemm_grid, 256, 0, stream>>>(
            x, h1b, h2b,
            Wpk + (size_t)r * 3072 * 8,
            b + (size_t)r * D_OUT,
            out + (size_t)r * D_OUT);
    }
}

// Round 6
// 810.208 us; speedup vs baseline: 12.2064x; 1.1244x over previous
//
#include <hip/hip_runtime.h>
#include <stdint.h>

#define N_NODES 100000
#define N_EDGES 1000000
#define D_IN 128
#define D_OUT 64
#define N_REL 4
#define OUT_STRIDE (N_REL * D_OUT)   // 256

#define M_SCAN (N_REL * N_NODES)     // 400000
#define SCHUNK 2048
#define NSB ((M_SCAN + SCHUNK - 1) / SCHUNK)   // 196 (<=256)
#define REL_CAP 2200000              // >=200 sigma above E[2M] masked entries

typedef short s16x8 __attribute__((ext_vector_type(8)));
typedef float f32x4 __attribute__((ext_vector_type(4)));

__device__ inline float b2f(unsigned short u) {
    union { unsigned int i; float f; } v;
    v.i = ((unsigned int)u) << 16;
    return v.f;
}
__device__ inline unsigned short f2b(float f) {
    union { float f; unsigned int i; } v;
    v.f = f;
    unsigned int r = v.i + 0x7FFF + ((v.i >> 16) & 1);   // rne
    return (unsigned short)(r >> 16);
}

// flag=1 if mask is 1-byte bools, 0 if int32
__global__ __launch_bounds__(256) void detect_mask_kernel(const uint8_t* __restrict__ mask,
                                                          int* __restrict__ flag) {
    int any = 0;
    for (int i = threadIdx.x; i < 65536; i += 256)
        if ((i & 3) && mask[i]) any = 1;
    if (any) atomicOr(flag, 1);
}

__device__ inline bool read_mask(const uint8_t* mask8, int bytemode, size_t idx) {
    return bytemode ? (mask8[idx] != 0) : (((const int*)mask8)[idx] != 0);
}

// all 4 masked in-degrees in ONE u64 atomic per edge (16-bit fields)
__global__ __launch_bounds__(256) void deg_kernel(const int* __restrict__ dst,
                                                  const uint8_t* __restrict__ mask,
                                                  const int* __restrict__ flag,
                                                  unsigned long long* __restrict__ degu) {
    int e = blockIdx.x * blockDim.x + threadIdx.x;
    if (e >= N_EDGES) return;
    int bm = *flag;
    int d = dst[e];
    unsigned long long inc = 0;
    if (read_mask(mask, bm, (size_t)0 * N_EDGES + e)) inc += 1ull;
    if (read_mask(mask, bm, (size_t)1 * N_EDGES + e)) inc += 1ull << 16;
    if (read_mask(mask, bm, (size_t)2 * N_EDGES + e)) inc += 1ull << 32;
    if (read_mask(mask, bm, (size_t)3 * N_EDGES + e)) inc += 1ull << 48;
    if (inc) atomicAdd(&degu[d], inc);
}

// norm[r*N+n] = 1/sqrt(max(deg_r[n],1))
__global__ __launch_bounds__(256) void norm_kernel(const unsigned long long* __restrict__ degu,
                                                   float* __restrict__ norm) {
    int n = blockIdx.x * blockDim.x + threadIdx.x;
    if (n >= N_NODES) return;
    unsigned long long u = degu[n];
#pragma unroll
    for (int r = 0; r < N_REL; ++r) {
        float dg = (float)((u >> (16 * r)) & 0xFFFF);
        norm[r * N_NODES + n] = 1.0f / sqrtf(fmaxf(dg, 1.0f));
    }
}

__device__ inline int scan_val(const unsigned long long* degu, int i) {
    int r = i / N_NODES;
    int n = i - r * N_NODES;
    return (int)((degu[n] >> (16 * r)) & 0xFFFF);
}

// ---- 3-phase exclusive scan over concatenated masked degrees [4N] ----
__global__ __launch_bounds__(256) void scan_reduce_kernel(const unsigned long long* __restrict__ degu,
                                                          int* __restrict__ bsum) {
    __shared__ int sm[256];
    int b = blockIdx.x, t = threadIdx.x;
    int base = b * SCHUNK + t * 8;
    int s = 0;
#pragma unroll
    for (int i = 0; i < 8; ++i) {
        int idx = base + i;
        if (idx < M_SCAN) s += scan_val(degu, idx);
    }
    sm[t] = s;
    __syncthreads();
    for (int st = 128; st > 0; st >>= 1) {
        if (t < st) sm[t] += sm[t + st];
        __syncthreads();
    }
    if (t == 0) bsum[b] = sm[0];
}

__global__ __launch_bounds__(256) void scan_mid_kernel(const int* __restrict__ bsum,
                                                       int* __restrict__ boff,
                                                       int* __restrict__ rel_rp) {
    __shared__ int sm[256];
    int t = threadIdx.x;
    int v = (t < NSB) ? bsum[t] : 0;
    sm[t] = v;
    __syncthreads();
    for (int st = 1; st < 256; st <<= 1) {
        int u = (t >= st) ? sm[t - st] : 0;
        __syncthreads();
        sm[t] += u;
        __syncthreads();
    }
    if (t < NSB) boff[t] = sm[t] - v;              // exclusive block offset
    if (t == NSB - 1) rel_rp[M_SCAN] = sm[t];      // total masked entries
}

__global__ __launch_bounds__(256) void scan_final_kernel(const unsigned long long* __restrict__ degu,
                                                         const int* __restrict__ boff,
                                                         int* __restrict__ rel_rp,
                                                         int* __restrict__ cursor) {
    __shared__ int sm[256];
    int b = blockIdx.x, t = threadIdx.x;
    int base = b * SCHUNK + t * 8;
    int v[8];
    int s = 0;
#pragma unroll
    for (int i = 0; i < 8; ++i) {
        int idx = base + i;
        v[i] = (idx < M_SCAN) ? scan_val(degu, idx) : 0;
        s += v[i];
    }
    sm[t] = s;
    __syncthreads();
    for (int st = 1; st < 256; st <<= 1) {
        int u = (t >= st) ? sm[t - st] : 0;
        __syncthreads();
        sm[t] += u;
        __syncthreads();
    }
    int run = sm[t] - s + boff[b];
#pragma unroll
    for (int i = 0; i < 8; ++i) {
        int idx = base + i;
        if (idx < M_SCAN) { rel_rp[idx] = run; cursor[idx] = run; run += v[i]; }
    }
}

// compacted per-relation CSR: only masked edges, store src only
__global__ __launch_bounds__(256) void fill_kernel(const int* __restrict__ src,
                                                   const int* __restrict__ dst,
                                                   const uint8_t* __restrict__ mask,
                                                   const int* __restrict__ flag,
                                                   int* __restrict__ cursor,
                                                   int* __restrict__ rel_src) {
    int e = blockIdx.x * blockDim.x + threadIdx.x;
    if (e >= N_EDGES) return;
    int bm = *flag;
    int s = src[e], d = dst[e];
#pragma unroll
    for (int r = 0; r < N_REL; ++r) {
        if (read_mask(mask, bm, (size_t)r * N_EDGES + e)) {
            int pos = atomicAdd(&cursor[r * N_NODES + d], 1);
            rel_src[pos] = s;
        }
    }
}

// pack W[r][384][64] fp32 -> Wpk frags [r][ks][nb][lane][8] bf16
__global__ __launch_bounds__(256) void pack_w_kernel(const float* __restrict__ W,
                                                     unsigned short* __restrict__ Wpk) {
    int t = blockIdx.x * blockDim.x + threadIdx.x;   // 12288
    if (t >= N_REL * 12 * 4 * 64) return;
    int lane = t & 63;
    int nb   = (t >> 6) & 3;
    int ks   = (t >> 8) % 12;
    int r    = t / 3072;
    const float* Wr = W + (size_t)r * 384 * 64;
    int k0 = ks * 32 + (lane >> 4) * 8;
    int n  = nb * 16 + (lane & 15);
    unsigned short* o = Wpk + (size_t)t * 8;
#pragma unroll
    for (int i = 0; i < 8; ++i)
        o[i] = f2b(Wr[(size_t)(k0 + i) * 64 + n]);
}

// x fp32 -> bf16
__global__ __launch_bounds__(256) void xb_kernel(const float* __restrict__ x,
                                                 unsigned short* __restrict__ xb) {
    int i = blockIdx.x * blockDim.x + threadIdx.x;
    if (i >= N_NODES * (D_IN / 4)) return;
    float4 v = ((const float4*)x)[i];
    ushort4 u;
    u.x = f2b(v.x); u.y = f2b(v.y); u.z = f2b(v.z); u.w = f2b(v.w);
    ((ushort4*)xb)[i] = u;
}

// one hop over compacted CSR: hout[d] = bf16( norm[d] * sum_e norm[src]*hin[src] )
template <int BF16IN>
__global__ __launch_bounds__(256) void gather_kernel(const void* __restrict__ hin_,
                                                     const int* __restrict__ rp,   // +r*N
                                                     const int* __restrict__ rel_src,
                                                     const float* __restrict__ normr,
                                                     unsigned short* __restrict__ hout) {
    int wid  = (blockIdx.x * blockDim.x + threadIdx.x) >> 6;   // node
    int lane = threadIdx.x & 63;
    if (wid >= N_NODES) return;
    int e0 = rp[wid], e1 = rp[wid + 1];
    float a0 = 0.0f, a1 = 0.0f;
    for (int base = e0; base < e1; base += 64) {
        int m = min(64, e1 - base);
        int   s_l = 0;
        float w_l = 0.0f;
        if (lane < m) {
            s_l = rel_src[base + lane];
            w_l = normr[s_l];
        }
        for (int k = 0; k < m; ++k) {
            int   s = __shfl(s_l, k);
            float w = __shfl(w_l, k);
            if (BF16IN) {
                unsigned int u = *(const unsigned int*)
                    ((const unsigned short*)hin_ + (size_t)s * D_IN + lane * 2);
                a0 += w * b2f((unsigned short)(u & 0xFFFF));
                a1 += w * b2f((unsigned short)(u >> 16));
            } else {
                float2 v = *(const float2*)
                    ((const float*)hin_ + (size_t)s * D_IN + lane * 2);
                a0 += w * v.x;
                a1 += w * v.y;
            }
        }
    }
    float c = normr[wid];
    unsigned int o = ((unsigned int)f2b(a1 * c) << 16) | f2b(a0 * c);
    *(unsigned int*)(hout + (size_t)wid * D_IN + lane * 2) = o;
}

// MFMA GEMM: out[n][j] = relu(bias[j] + sum_k [x|h1|h2][n][k] W[k][j])
template <int XB16>
__global__ __launch_bounds__(256) void gemm_mfma_kernel(const void* __restrict__ x_,
                                                        const unsigned short* __restrict__ h1b,
                                                        const unsigned short* __restrict__ h2b,
                                                        const unsigned short* __restrict__ Wpk,
                                                        const float* __restrict__ bias,
                                                        float* __restrict__ out) {
    const int wave = threadIdx.x >> 6;
    const int lane = threadIdx.x & 63;
    const int rb   = blockIdx.x * 64 + wave * 16;
    const int row  = min(rb + (lane & 15), N_NODES - 1);
    const int kq   = (lane >> 4) * 8;

    f32x4 acc0 = {0.f, 0.f, 0.f, 0.f};
    f32x4 acc1 = {0.f, 0.f, 0.f, 0.f};
    f32x4 acc2 = {0.f, 0.f, 0.f, 0.f};
    f32x4 acc3 = {0.f, 0.f, 0.f, 0.f};

    const s16x8* Wf = (const s16x8*)Wpk;

#pragma unroll
    for (int ks = 0; ks < 12; ++ks) {
        s16x8 a;
        const int koff = (ks & 3) * 32 + kq;
        if (ks < 4) {
            if (XB16) {
                a = *(const s16x8*)((const unsigned short*)x_ + (size_t)row * D_IN + koff);
            } else {
                const float* p = (const float*)x_ + (size_t)row * D_IN + koff;
                float4 f0 = *(const float4*)p;
                float4 f1 = *(const float4*)(p + 4);
                a[0] = (short)f2b(f0.x); a[1] = (short)f2b(f0.y);
                a[2] = (short)f2b(f0.z); a[3] = (short)f2b(f0.w);
                a[4] = (short)f2b(f1.x); a[5] = (short)f2b(f1.y);
                a[6] = (short)f2b(f1.z); a[7] = (short)f2b(f1.w);
            }
        } else {
            const unsigned short* hp = (ks < 8) ? h1b : h2b;
            a = *(const s16x8*)(hp + (size_t)row * D_IN + koff);
        }
        const s16x8* bks = Wf + ks * 256 + lane;
        acc0 = __builtin_amdgcn_mfma_f32_16x16x32_bf16(a, bks[0],   acc0, 0, 0, 0);
        acc1 = __builtin_amdgcn_mfma_f32_16x16x32_bf16(a, bks[64],  acc1, 0, 0, 0);
        acc2 = __builtin_amdgcn_mfma_f32_16x16x32_bf16(a, bks[128], acc2, 0, 0, 0);
        acc3 = __builtin_amdgcn_mfma_f32_16x16x32_bf16(a, bks[192], acc3, 0, 0, 0);
    }

    const int orow0 = rb + (lane >> 4) * 4;
    const int jc    = lane & 15;
    f32x4 accs[4] = {acc0, acc1, acc2, acc3};
#pragma unroll
    for (int nb = 0; nb < 4; ++nb) {
        float bz = bias[nb * 16 + jc];
#pragma unroll
        for (int i = 0; i < 4; ++i) {
            int n = orow0 + i;
            if (n < N_NODES)
                out[(size_t)n * OUT_STRIDE + nb * 16 + jc] = fmaxf(accs[nb][i] + bz, 0.0f);
        }
    }
}

extern "C" void kernel_launch(void* const* d_in, const int* in_sizes, int n_in,
                              void* d_out, int out_size, void* d_ws, size_t ws_size,
                              hipStream_t stream) {
    const float*   x    = (const float*)d_in[0];
    const int*     src  = (const int*)d_in[1];
    const int*     dst  = (const int*)d_in[2];
    const uint8_t* mask = (const uint8_t*)d_in[3];
    const float*   W    = (const float*)d_in[4];     // [4][384][64]
    const float*   b    = (const float*)d_in[5];     // [4][64]
    float*         out  = (float*)d_out;             // [N][256]

    // ws: flag[64]i | degu[N]u64 | norm[4N]f | rel_rp[4N+16]i | bsum[256] |
    //     boff[256] | rel_src[REL_CAP]i | Wpk bf16 | h1b bf16 | h2b bf16 |
    //     xb bf16 (optional).  cursor aliases h1b (dead before gathers).
    int*                flag    = (int*)d_ws;
    unsigned long long* degu    = (unsigned long long*)((char*)d_ws + 256);
    float*              norm    = (float*)(degu + N_NODES);
    int*                rel_rp  = (int*)(norm + (size_t)N_REL * N_NODES);
    int*                bsum    = rel_rp + M_SCAN + 16;
    int*                boff    = bsum + 256;
    int*                rel_src = boff + 256;
    unsigned short*     Wpk     = (unsigned short*)(rel_src + REL_CAP);
    unsigned short*     h1b     = Wpk + 12288 * 8;
    unsigned short*     h2b     = h1b + (size_t)N_NODES * D_IN;
    unsigned short*     xb      = h2b + (size_t)N_NODES * D_IN;
    int*                cursor  = (int*)h1b;   // alias: used only pre-gather

    const size_t need_xb = (size_t)((char*)(xb + (size_t)N_NODES * D_IN) - (char*)d_ws);
    const int use_xb = (ws_size >= need_xb);

    // zero flag + degu
    hipMemsetAsync(d_ws, 0, 256 + (size_t)N_NODES * sizeof(unsigned long long), stream);

    detect_mask_kernel<<<1, 256, 0, stream>>>(mask, flag);
    deg_kernel<<<(N_EDGES + 255) / 256, 256, 0, stream>>>(dst, mask, flag, degu);
    norm_kernel<<<(N_NODES + 255) / 256, 256, 0, stream>>>(degu, norm);

    scan_reduce_kernel<<<NSB, 256, 0, stream>>>(degu, bsum);
    scan_mid_kernel<<<1, 256, 0, stream>>>(bsum, boff, rel_rp);
    scan_final_kernel<<<NSB, 256, 0, stream>>>(degu, boff, rel_rp, cursor);

    fill_kernel<<<(N_EDGES + 255) / 256, 256, 0, stream>>>(src, dst, mask, flag,
                                                           cursor, rel_src);
    pack_w_kernel<<<48, 256, 0, stream>>>(W, Wpk);
    if (use_xb)
        xb_kernel<<<(N_NODES * (D_IN / 4) + 255) / 256, 256, 0, stream>>>(x, xb);

    const int gather_grid = (N_NODES * 64 + 255) / 256;   // 1 wave per node
    const int gemm_grid   = (N_NODES + 63) / 64;

    for (int r = 0; r < N_REL; ++r) {
        const float* nr  = norm + (size_t)r * N_NODES;
        const int*   rpr = rel_rp + (size_t)r * N_NODES;

        if (use_xb)
            gather_kernel<1><<<gather_grid, 256, 0, stream>>>(xb, rpr, rel_src, nr, h1b);
        else
            gather_kernel<0><<<gather_grid, 256, 0, stream>>>(x, rpr, rel_src, nr, h1b);

        gather_kernel<1><<<gather_grid, 256, 0, stream>>>(h1b, rpr, rel_src, nr, h2b);

        if (use_xb)
            gemm_mfma_kernel<1><<<gemm_grid, 256, 0, stream>>>(
                xb, h1b, h2b, Wpk + (size_t)r * 3072 * 8,
                b + (size_t)r * D_OUT, out + (size_t)r * D_OUT);
        else
            gemm_mfma_kernel<0><<<gemm_grid, 256, 0, stream>>>(
                x, h1b, h2b, Wpk + (size_t)r * 3072 * 8,
                b + (size_t)r * D_OUT, out + (size_t)r * D_OUT);
    }
}

// Round 9
// 744.495 us; speedup vs baseline: 13.2838x; 1.0883x over previous
//
#include <hip/hip_runtime.h>
#include <stdint.h>

#define N_NODES 100000
#define N_EDGES 1000000
#define D_IN 128
#define D_OUT 64
#define N_REL 4
#define OUT_STRIDE (N_REL * D_OUT)   // 256

#define M_SCAN (N_REL * N_NODES)     // 400000
#define SCHUNK 2048
#define NSB ((M_SCAN + SCHUNK - 1) / SCHUNK)   // 196 (<=256)
#define REL_CAP 2200000              // >=200 sigma above E[2M] masked entries

typedef short s16x8 __attribute__((ext_vector_type(8)));
typedef float f32x4 __attribute__((ext_vector_type(4)));

__device__ inline float b2f(unsigned short u) {
    union { unsigned int i; float f; } v;
    v.i = ((unsigned int)u) << 16;
    return v.f;
}
__device__ inline unsigned short f2b(float f) {
    union { float f; unsigned int i; } v;
    v.f = f;
    unsigned int r = v.i + 0x7FFF + ((v.i >> 16) & 1);   // rne
    return (unsigned short)(r >> 16);
}

// flag=1 if mask is 1-byte bools, 0 if int32
__global__ __launch_bounds__(256) void detect_mask_kernel(const uint8_t* __restrict__ mask,
                                                          int* __restrict__ flag) {
    int any = 0;
    for (int i = threadIdx.x; i < 65536; i += 256)
        if ((i & 3) && mask[i]) any = 1;
    if (any) atomicOr(flag, 1);
}

__device__ inline bool read_mask(const uint8_t* mask8, int bytemode, size_t idx) {
    return bytemode ? (mask8[idx] != 0) : (((const int*)mask8)[idx] != 0);
}

// all 4 masked in-degrees in ONE u64 atomic per edge (16-bit fields)
__global__ __launch_bounds__(256) void deg_kernel(const int* __restrict__ dst,
                                                  const uint8_t* __restrict__ mask,
                                                  const int* __restrict__ flag,
                                                  unsigned long long* __restrict__ degu) {
    int e = blockIdx.x * blockDim.x + threadIdx.x;
    if (e >= N_EDGES) return;
    int bm = *flag;
    int d = dst[e];
    unsigned long long inc = 0;
    if (read_mask(mask, bm, (size_t)0 * N_EDGES + e)) inc += 1ull;
    if (read_mask(mask, bm, (size_t)1 * N_EDGES + e)) inc += 1ull << 16;
    if (read_mask(mask, bm, (size_t)2 * N_EDGES + e)) inc += 1ull << 32;
    if (read_mask(mask, bm, (size_t)3 * N_EDGES + e)) inc += 1ull << 48;
    if (inc) atomicAdd(&degu[d], inc);
}

// norm[r*N+n] = 1/sqrt(max(deg_r[n],1))
__global__ __launch_bounds__(256) void norm_kernel(const unsigned long long* __restrict__ degu,
                                                   float* __restrict__ norm) {
    int n = blockIdx.x * blockDim.x + threadIdx.x;
    if (n >= N_NODES) return;
    unsigned long long u = degu[n];
#pragma unroll
    for (int r = 0; r < N_REL; ++r) {
        float dg = (float)((u >> (16 * r)) & 0xFFFF);
        norm[r * N_NODES + n] = 1.0f / sqrtf(fmaxf(dg, 1.0f));
    }
}

__device__ inline int scan_val(const unsigned long long* degu, int i) {
    int r = i / N_NODES;
    int n = i - r * N_NODES;
    return (int)((degu[n] >> (16 * r)) & 0xFFFF);
}

// ---- 3-phase exclusive scan over concatenated masked degrees [4N] ----
__global__ __launch_bounds__(256) void scan_reduce_kernel(const unsigned long long* __restrict__ degu,
                                                          int* __restrict__ bsum) {
    __shared__ int sm[256];
    int b = blockIdx.x, t = threadIdx.x;
    int base = b * SCHUNK + t * 8;
    int s = 0;
#pragma unroll
    for (int i = 0; i < 8; ++i) {
        int idx = base + i;
        if (idx < M_SCAN) s += scan_val(degu, idx);
    }
    sm[t] = s;
    __syncthreads();
    for (int st = 128; st > 0; st >>= 1) {
        if (t < st) sm[t] += sm[t + st];
        __syncthreads();
    }
    if (t == 0) bsum[b] = sm[0];
}

__global__ __launch_bounds__(256) void scan_mid_kernel(const int* __restrict__ bsum,
                                                       int* __restrict__ boff,
                                                       int* __restrict__ rel_rp) {
    __shared__ int sm[256];
    int t = threadIdx.x;
    int v = (t < NSB) ? bsum[t] : 0;
    sm[t] = v;
    __syncthreads();
    for (int st = 1; st < 256; st <<= 1) {
        int u = (t >= st) ? sm[t - st] : 0;
        __syncthreads();
        sm[t] += u;
        __syncthreads();
    }
    if (t < NSB) boff[t] = sm[t] - v;              // exclusive block offset
    if (t == NSB - 1) rel_rp[M_SCAN] = sm[t];      // total masked entries
}

__global__ __launch_bounds__(256) void scan_final_kernel(const unsigned long long* __restrict__ degu,
                                                         const int* __restrict__ boff,
                                                         int* __restrict__ rel_rp,
                                                         int* __restrict__ cursor) {
    __shared__ int sm[256];
    int b = blockIdx.x, t = threadIdx.x;
    int base = b * SCHUNK + t * 8;
    int v[8];
    int s = 0;
#pragma unroll
    for (int i = 0; i < 8; ++i) {
        int idx = base + i;
        v[i] = (idx < M_SCAN) ? scan_val(degu, idx) : 0;
        s += v[i];
    }
    sm[t] = s;
    __syncthreads();
    for (int st = 1; st < 256; st <<= 1) {
        int u = (t >= st) ? sm[t - st] : 0;
        __syncthreads();
        sm[t] += u;
        __syncthreads();
    }
    int run = sm[t] - s + boff[b];
#pragma unroll
    for (int i = 0; i < 8; ++i) {
        int idx = base + i;
        if (idx < M_SCAN) { rel_rp[idx] = run; cursor[idx] = run; run += v[i]; }
    }
}

// compacted per-relation CSR: only masked edges, store src only
__global__ __launch_bounds__(256) void fill_kernel(const int* __restrict__ src,
                                                   const int* __restrict__ dst,
                                                   const uint8_t* __restrict__ mask,
                                                   const int* __restrict__ flag,
                                                   int* __restrict__ cursor,
                                                   int* __restrict__ rel_src) {
    int e = blockIdx.x * blockDim.x + threadIdx.x;
    if (e >= N_EDGES) return;
    int bm = *flag;
    int s = src[e], d = dst[e];
#pragma unroll
    for (int r = 0; r < N_REL; ++r) {
        if (read_mask(mask, bm, (size_t)r * N_EDGES + e)) {
            int pos = atomicAdd(&cursor[r * N_NODES + d], 1);
            rel_src[pos] = s;
        }
    }
}

// pack W[r][384][64] fp32 -> Wpk frags [r][ks][nb][lane][8] bf16
__global__ __launch_bounds__(256) void pack_w_kernel(const float* __restrict__ W,
                                                     unsigned short* __restrict__ Wpk) {
    int t = blockIdx.x * blockDim.x + threadIdx.x;   // 12288
    if (t >= N_REL * 12 * 4 * 64) return;
    int lane = t & 63;
    int nb   = (t >> 6) & 3;
    int ks   = (t >> 8) % 12;
    int r    = t / 3072;
    const float* Wr = W + (size_t)r * 384 * 64;
    int k0 = ks * 32 + (lane >> 4) * 8;
    int n  = nb * 16 + (lane & 15);
    unsigned short* o = Wpk + (size_t)t * 8;
#pragma unroll
    for (int i = 0; i < 8; ++i)
        o[i] = f2b(Wr[(size_t)(k0 + i) * 64 + n]);
}

// x fp32 -> bf16
__global__ __launch_bounds__(256) void xb_kernel(const float* __restrict__ x,
                                                 unsigned short* __restrict__ xb) {
    int i = blockIdx.x * blockDim.x + threadIdx.x;
    if (i >= N_NODES * (D_IN / 4)) return;
    float4 v = ((const float4*)x)[i];
    ushort4 u;
    u.x = f2b(v.x); u.y = f2b(v.y); u.z = f2b(v.z); u.w = f2b(v.w);
    ((ushort4*)xb)[i] = u;
}

// one hop over compacted CSR: hout[d] = bf16( norm[d] * sum_e norm[src]*hin[src] )
// wave per node; 4 edges in flight: 16-lane groups, 8 features/lane.
// ALL __shfl executed unconditionally (full exec mask).
template <int BF16IN>
__global__ __launch_bounds__(256) void gather_kernel(const void* __restrict__ hin_,
                                                     const int* __restrict__ rp,   // +r*N
                                                     const int* __restrict__ rel_src,
                                                     const float* __restrict__ normr,
                                                     unsigned short* __restrict__ hout) {
    const int lane = threadIdx.x & 63;
    const int wid  = (blockIdx.x * blockDim.x + threadIdx.x) >> 6;   // node
    if (wid >= N_NODES) return;
    const int g  = lane >> 4;              // edge-slot group 0..3
    const int fb = (lane & 15) * 8;        // feature base (8 feats/lane)

    float a[8];
#pragma unroll
    for (int j = 0; j < 8; ++j) a[j] = 0.0f;

    int e0 = rp[wid], e1 = rp[wid + 1];
    for (int base = e0; base < e1; base += 64) {
        int m = min(64, e1 - base);
        int   s_l = (lane < m) ? rel_src[base + lane] : 0;
        float w_l = (lane < m) ? normr[s_l] : 0.0f;

        for (int t = 0; t * 4 < m; ++t) {
            int ei = t * 4 + g;                    // <= 63 always
            int   s = __shfl(s_l, ei);             // unconditional, full mask
            float w = __shfl(w_l, ei);
            if (ei < m) {                          // uniform per 16-lane group
                if (BF16IN) {
                    s16x8 v = *(const s16x8*)((const unsigned short*)hin_ +
                                              (size_t)s * D_IN + fb);
#pragma unroll
                    for (int j = 0; j < 8; ++j)
                        a[j] += w * b2f((unsigned short)v[j]);
                } else {
                    const float* xp = (const float*)hin_ + (size_t)s * D_IN + fb;
                    float4 v0 = *(const float4*)xp;
                    float4 v1 = *(const float4*)(xp + 4);
                    a[0] += w * v0.x; a[1] += w * v0.y;
                    a[2] += w * v0.z; a[3] += w * v0.w;
                    a[4] += w * v1.x; a[5] += w * v1.y;
                    a[6] += w * v1.z; a[7] += w * v1.w;
                }
            }
        }
    }

    // combine the 4 edge-slot groups (butterfly over lane bits 4,5)
#pragma unroll
    for (int j = 0; j < 8; ++j) {
        a[j] += __shfl_xor(a[j], 16);
        a[j] += __shfl_xor(a[j], 32);
    }
    float c = normr[wid];
    if (lane < 16) {
        s16x8 r;
#pragma unroll
        for (int j = 0; j < 8; ++j) r[j] = (short)f2b(a[j] * c);
        *(s16x8*)(hout + (size_t)wid * D_IN + lane * 8) = r;
    }
}

// MFMA GEMM: out[n][j] = relu(bias[j] + sum_k [x|h1|h2][n][k] W[k][j])
template <int XB16>
__global__ __launch_bounds__(256) void gemm_mfma_kernel(const void* __restrict__ x_,
                                                        const unsigned short* __restrict__ h1b,
                                                        const unsigned short* __restrict__ h2b,
                                                        const unsigned short* __restrict__ Wpk,
                                                        const float* __restrict__ bias,
                                                        float* __restrict__ out) {
    const int wave = threadIdx.x >> 6;
    const int lane = threadIdx.x & 63;
    const int rb   = blockIdx.x * 64 + wave * 16;
    const int row  = min(rb + (lane & 15), N_NODES - 1);
    const int kq   = (lane >> 4) * 8;

    f32x4 acc0 = {0.f, 0.f, 0.f, 0.f};
    f32x4 acc1 = {0.f, 0.f, 0.f, 0.f};
    f32x4 acc2 = {0.f, 0.f, 0.f, 0.f};
    f32x4 acc3 = {0.f, 0.f, 0.f, 0.f};

    const s16x8* Wf = (const s16x8*)Wpk;

#pragma unroll
    for (int ks = 0; ks < 12; ++ks) {
        s16x8 a;
        const int koff = (ks & 3) * 32 + kq;
        if (ks < 4) {
            if (XB16) {
                a = *(const s16x8*)((const unsigned short*)x_ + (size_t)row * D_IN + koff);
            } else {
                const float* p = (const float*)x_ + (size_t)row * D_IN + koff;
                float4 f0 = *(const float4*)p;
                float4 f1 = *(const float4*)(p + 4);
                a[0] = (short)f2b(f0.x); a[1] = (short)f2b(f0.y);
                a[2] = (short)f2b(f0.z); a[3] = (short)f2b(f0.w);
                a[4] = (short)f2b(f1.x); a[5] = (short)f2b(f1.y);
                a[6] = (short)f2b(f1.z); a[7] = (short)f2b(f1.w);
            }
        } else {
            const unsigned short* hp = (ks < 8) ? h1b : h2b;
            a = *(const s16x8*)(hp + (size_t)row * D_IN + koff);
        }
        const s16x8* bks = Wf + ks * 256 + lane;
        acc0 = __builtin_amdgcn_mfma_f32_16x16x32_bf16(a, bks[0],   acc0, 0, 0, 0);
        acc1 = __builtin_amdgcn_mfma_f32_16x16x32_bf16(a, bks[64],  acc1, 0, 0, 0);
        acc2 = __builtin_amdgcn_mfma_f32_16x16x32_bf16(a, bks[128], acc2, 0, 0, 0);
        acc3 = __builtin_amdgcn_mfma_f32_16x16x32_bf16(a, bks[192], acc3, 0, 0, 0);
    }

    const int orow0 = rb + (lane >> 4) * 4;
    const int jc    = lane & 15;
    f32x4 accs[4] = {acc0, acc1, acc2, acc3};
#pragma unroll
    for (int nb = 0; nb < 4; ++nb) {
        float bz = bias[nb * 16 + jc];
#pragma unroll
        for (int i = 0; i < 4; ++i) {
            int n = orow0 + i;
            if (n < N_NODES)
                out[(size_t)n * OUT_STRIDE + nb * 16 + jc] = fmaxf(accs[nb][i] + bz, 0.0f);
        }
    }
}

extern "C" void kernel_launch(void* const* d_in, const int* in_sizes, int n_in,
                              void* d_out, int out_size, void* d_ws, size_t ws_size,
                              hipStream_t stream) {
    const float*   x    = (const float*)d_in[0];
    const int*     src  = (const int*)d_in[1];
    const int*     dst  = (const int*)d_in[2];
    const uint8_t* mask = (const uint8_t*)d_in[3];
    const float*   W    = (const float*)d_in[4];     // [4][384][64]
    const float*   b    = (const float*)d_in[5];     // [4][64]
    float*         out  = (float*)d_out;             // [N][256]

    // ws: flag[64]i | degu[N]u64 | norm[4N]f | rel_rp[4N+16]i | bsum[256] |
    //     boff[256] | rel_src[REL_CAP]i | Wpk bf16 | h1b bf16 | h2b bf16 |
    //     xb bf16 (optional).  cursor aliases h1b (dead before gathers).
    int*                flag    = (int*)d_ws;
    unsigned long long* degu    = (unsigned long long*)((char*)d_ws + 256);
    float*              norm    = (float*)(degu + N_NODES);
    int*                rel_rp  = (int*)(norm + (size_t)N_REL * N_NODES);
    int*                bsum    = rel_rp + M_SCAN + 16;
    int*                boff    = bsum + 256;
    int*                rel_src = boff + 256;
    unsigned short*     Wpk     = (unsigned short*)(rel_src + REL_CAP);
    unsigned short*     h1b     = Wpk + 12288 * 8;
    unsigned short*     h2b     = h1b + (size_t)N_NODES * D_IN;
    unsigned short*     xb      = h2b + (size_t)N_NODES * D_IN;
    int*                cursor  = (int*)h1b;   // alias: used only pre-gather

    const size_t need_xb = (size_t)((char*)(xb + (size_t)N_NODES * D_IN) - (char*)d_ws);
    const int use_xb = (ws_size >= need_xb);

    // zero flag + degu
    hipMemsetAsync(d_ws, 0, 256 + (size_t)N_NODES * sizeof(unsigned long long), stream);

    detect_mask_kernel<<<1, 256, 0, stream>>>(mask, flag);
    deg_kernel<<<(N_EDGES + 255) / 256, 256, 0, stream>>>(dst, mask, flag, degu);
    norm_kernel<<<(N_NODES + 255) / 256, 256, 0, stream>>>(degu, norm);

    scan_reduce_kernel<<<NSB, 256, 0, stream>>>(degu, bsum);
    scan_mid_kernel<<<1, 256, 0, stream>>>(bsum, boff, rel_rp);
    scan_final_kernel<<<NSB, 256, 0, stream>>>(degu, boff, rel_rp, cursor);

    fill_kernel<<<(N_EDGES + 255) / 256, 256, 0, stream>>>(src, dst, mask, flag,
                                                           cursor, rel_src);
    pack_w_kernel<<<48, 256, 0, stream>>>(W, Wpk);
    if (use_xb)
        xb_kernel<<<(N_NODES * (D_IN / 4) + 255) / 256, 256, 0, stream>>>(x, xb);

    const int gather_grid = (N_NODES * 64 + 255) / 256;   // 1 wave per node
    const int gemm_grid   = (N_NODES + 63) / 64;

    for (int r = 0; r < N_REL; ++r) {
        const float* nr  = norm + (size_t)r * N_NODES;
        const int*   rpr = rel_rp + (size_t)r * N_NODES;

        if (use_xb)
            gather_kernel<1><<<gather_grid, 256, 0, stream>>>(xb, rpr, rel_src, nr, h1b);
        else
            gather_kernel<0><<<gather_grid, 256, 0, stream>>>(x, rpr, rel_src, nr, h1b);

        gather_kernel<1><<<gather_grid, 256, 0, stream>>>(h1b, rpr, rel_src, nr, h2b);

        if (use_xb)
            gemm_mfma_kernel<1><<<gemm_grid, 256, 0, stream>>>(
                xb, h1b, h2b, Wpk + (size_t)r * 3072 * 8,
                b + (size_t)r * D_OUT, out + (size_t)r * D_OUT);
        else
            gemm_mfma_kernel<0><<<gemm_grid, 256, 0, stream>>>(
                x, h1b, h2b, Wpk + (size_t)r * 3072 * 8,
                b + (size_t)r * D_OUT, out + (size_t)r * D_OUT);
    }
}